// Round 13
// baseline (264.308 us; speedup 1.0000x reference)
//
#include <hip/hip_runtime.h>
#include <hip/hip_bf16.h>
#include <cstdint>

#define NTOPK 64
#define A_TOT 340
#define MS 28

// d_out element offsets (f32)
#define OFF_SCORES 0
#define OFF_BOXES  128
#define OFF_LABELS 640
#define OFF_MASKS  768
#define OFF_KEEP   33555200ull

typedef __attribute__((ext_vector_type(4))) float f32x4;
typedef __attribute__((ext_vector_type(2))) float f32x2;
typedef long fp8x8;   // 8 x e4m3 in one 64-bit reg pair

__device__ __forceinline__ float sigmoidf_(float x) { return 1.f / (1.f + expf(-x)); }
__device__ __forceinline__ float bf2f(unsigned u) {
  return __uint_as_float(u << 16);
}
__device__ __forceinline__ unsigned short f2bf(float f) {
  __hip_bfloat16 h = __float2bfloat16(f);  // RNE
  return *(unsigned short*)&h;
}

// ---- Kernel P: fused prep. blocks 0-1: decode+NMS; 2-129: weight transpose;
// ---- 130-385: merged feature build; 386-897: mask canvas zero-fill.
__global__ __launch_bounds__(256) void k_prep(
    const float* __restrict__ p0, const float* __restrict__ p1,
    const float* __restrict__ p2, const float* __restrict__ p3,
    const float* __restrict__ f0, const float* __restrict__ f1,
    const float* __restrict__ f2, const float* __restrict__ f3,
    const float* __restrict__ w1,
    float* __restrict__ out,
    float* __restrict__ ws_boxes, int* __restrict__ ws_keep,
    int* __restrict__ ws_boxint,
    unsigned char* __restrict__ wt, unsigned short* __restrict__ mg)
{
  __shared__ __align__(16) char smem_raw[128 * 260 * 2];
  const int bid = blockIdx.x;
  const int t = threadIdx.x;

  if (bid >= 386) {
    // ---- mask canvas zero-fill: one quarter (128 rows) of one box
    const int j = bid - 386;                 // 0..511
    float* zb = out + OFF_MASKS + (size_t)(j >> 2) * 262144 +
                (size_t)(j & 3) * 65536;
    f32x4 z = {0.f, 0.f, 0.f, 0.f};
    f32x4* p = (f32x4*)zb;
    for (int e = t; e < 16384; e += 256)
      __builtin_nontemporal_store(z, p + e);
    return;
  }

  if (bid < 2) {
    // ---------------- decode + stable top-64 + shfl NMS ----------------
    const int b = bid;
    float* sc = (float*)smem_raw;                    // [A_TOT]
    float(*bx)[4] = (float(*)[4])(sc + A_TOT);       // [A_TOT][4]
    float* tk_score = (float*)(bx + A_TOT);          // [64]
    float(*tk_box)[4] = (float(*)[4])(tk_score + 64);

    for (int a = t; a < A_TOT; a += 256) {
      const float* pp; int W, HW, la; float stride;
      if (a < 256)      { pp = p0; W = 16; HW = 256; la = a;       stride = 32.f;  }
      else if (a < 320) { pp = p1; W = 8;  HW = 64;  la = a - 256; stride = 64.f;  }
      else if (a < 336) { pp = p2; W = 4;  HW = 16;  la = a - 320; stride = 128.f; }
      else              { pp = p3; W = 2;  HW = 4;   la = a - 336; stride = 256.f; }
      const float* base = pp + (size_t)b * 6 * HW + la;
      float v0 = base[0], v1 = base[HW], v2 = base[2 * HW], v3 = base[3 * HW], v4 = base[4 * HW];
      int gx = la % W, gy = la / W;
      float cx = (v0 + (float)gx) * stride;
      float cy = (v1 + (float)gy) * stride;
      float w_ = expf(v2) * stride;
      float h_ = expf(v3) * stride;
      float score = sigmoidf_(v4);
      sc[a] = (score > 0.5f) ? score : 0.f;
      bx[a][0] = cx - 0.5f * w_;
      bx[a][1] = cy - 0.5f * h_;
      bx[a][2] = cx + 0.5f * w_;
      bx[a][3] = cy + 0.5f * h_;
    }
    __syncthreads();

    // stable top-k by rank counting (ties -> lower index, like lax.top_k)
    for (int a = t; a < A_TOT; a += 256) {
      float my = sc[a];
      int rank = 0;
      for (int j = 0; j < A_TOT; ++j) {
        float o = sc[j];
        rank += (o > my) || (o == my && j < a);
      }
      if (rank < NTOPK) {
        tk_score[rank] = my;
        tk_box[rank][0] = bx[a][0];
        tk_box[rank][1] = bx[a][1];
        tk_box[rank][2] = bx[a][2];
        tk_box[rank][3] = bx[a][3];
      }
    }
    __syncthreads();

    // wave-synchronous sequential NMS on wave 0
    if (t < NTOPK) {
      float x0 = tk_box[t][0], y0 = tk_box[t][1];
      float x1 = tk_box[t][2], y1 = tk_box[t][3];
      float s = tk_score[t];
      float area = fmaxf(x1 - x0, 0.f) * fmaxf(y1 - y0, 0.f);
      int keep = (s > 0.5f) ? 1 : 0;
      for (int i = 0; i < NTOPK - 1; ++i) {
        int   ki = __shfl(keep, i);
        float a0 = __shfl(x0, i);
        float c0 = __shfl(y0, i);
        float a1 = __shfl(x1, i);
        float c1 = __shfl(y1, i);
        float ai = __shfl(area, i);
        if (ki && t > i && keep) {
          float ix0 = fmaxf(a0, x0), iy0 = fmaxf(c0, y0);
          float ix1 = fminf(a1, x1), iy1 = fminf(c1, y1);
          float inter = fmaxf(ix1 - ix0, 0.f) * fmaxf(iy1 - iy0, 0.f);
          float uni = ai + area - inter;
          float iou = inter / fmaxf(uni, 1e-9f);
          if (iou > 0.5f) keep = 0;
        }
      }
      int box = b * NTOPK + t;
      out[OFF_SCORES + box] = keep ? s : 0.f;
      float bv[4] = {x0, y0, x1, y1};
      #pragma unroll
      for (int c = 0; c < 4; ++c) {
        out[OFF_BOXES + box * 4 + c] = bv[c];
        ws_boxes[box * 4 + c] = bv[c];
        float bc = fminf(fmaxf(bv[c], 0.f), 511.f);
        ws_boxint[box * 4 + c] = (int)bc;
      }
      out[OFF_LABELS + box] = 0.f;
      out[OFF_KEEP + box] = keep ? 1.f : 0.f;
      ws_keep[box] = keep;
    }
    return;
  }

  if (bid < 130) {
    // -- w1 f32 [co][ci][3][3] -> wt fp8 [chunk][cq][tap][co32][ci32] with
    // -- octet swizzle baked in: octet slot = (cil>>3) ^ ((col>>2)&3).
    const int co = bid - 2;
    const int ci = t;            // 0..255
    const int c = ci >> 5, cil = ci & 31;
    const int cq = co >> 5, col = co & 31;
    const int slot = ((cil >> 3) ^ ((col >> 2) & 3)) * 8 + (cil & 7);
    const float* src = w1 + ((size_t)co * 256 + ci) * 9;
    #pragma unroll
    for (int tap = 0; tap < 9; ++tap) {
      unsigned u = __builtin_amdgcn_cvt_pk_fp8_f32(src[tap], 0.f, 0, false);
      wt[(((size_t)(c * 4 + cq) * 9 + tap)) * 1024 + col * 32 + slot] =
          (unsigned char)(u & 0xff);
    }
    return;
  }

  // -------- merged[b][y][x][c] bf16 build --------
  {
    const int idx = bid - 130;
    const int b = idx >> 7;
    const int y = idx & 127;
    unsigned short* tile = (unsigned short*)smem_raw;   // [128*260]
    const int x = t & 127, ch = t >> 7;

    {
      const float* src = f0 + ((size_t)b * 64) * 16384 + y * 128 + x;
      for (int cc = 0; cc < 32; ++cc) {
        int cl = ch * 32 + cc;
        tile[x * 260 + cl] = f2bf(src[(size_t)cl * 16384]);
      }
    }
    {
      const float* src = f1 + ((size_t)b * 64) * 4096 + (y >> 1) * 64 + (x >> 1);
      for (int cc = 0; cc < 32; ++cc) {
        int cl = ch * 32 + cc;
        tile[x * 260 + 64 + cl] = f2bf(src[(size_t)cl * 4096]);
      }
    }
    {
      const float* src = f2 + ((size_t)b * 64) * 1024 + (y >> 2) * 32 + (x >> 2);
      for (int cc = 0; cc < 32; ++cc) {
        int cl = ch * 32 + cc;
        tile[x * 260 + 128 + cl] = f2bf(src[(size_t)cl * 1024]);
      }
    }
    {
      const float* src = f3 + ((size_t)b * 64) * 256 + (y >> 3) * 16 + (x >> 3);
      for (int cc = 0; cc < 32; ++cc) {
        int cl = ch * 32 + cc;
        tile[x * 260 + 192 + cl] = f2bf(src[(size_t)cl * 256]);
      }
    }
    __syncthreads();
    unsigned short* dst = mg + (((size_t)b * 128 + y) * 128) * 256;
    for (int it = 0; it < 32; ++it) {
      int qq = t + it * 256;
      int xx = qq >> 6, cg = qq & 63;
      *(ushort4*)(dst + xx * 256 + cg * 4) = *(ushort4*)&tile[xx * 260 + cg * 4];
    }
  }
}

// ==== Kernel F v13: v10 with the WHOLE-B gather hoisted out of the chunk
// loop. All 8 chunks' B tiles (72KB) are gathered ONCE at block start, in a
// register-light phase (before acc/ga exist -> compiler can pipeline loads;
// v11/v12 spilled because gather shared the chunk loop's live range).
// Per-chunk loop is then {writeA, sync, issueA(c+1), MFMA, sync} -- near-zero
// VALU on the serial path. LDS 110.5KB -> 1 block/CU (matches observed ~1
// active heavy block/CU). launch_bounds(512,2): 256-VGPR budget.
// Gather math = v10's exact scalar form (v12's packed form regressed).
__global__ __launch_bounds__(512, 2) void k_conv(
    const unsigned short* __restrict__ mg,  // merged [b][y][x][c] bf16
    const unsigned char* __restrict__ wt,   // [c][cq][tap][co32][ci32^swz]
    const float* __restrict__ b1, const float* __restrict__ w2,
    const float* __restrict__ b2,
    const float* __restrict__ ws_boxes, const int* __restrict__ ws_keep,
    const int* __restrict__ ws_boxint,
    float* __restrict__ out)
{
  const int bid = blockIdx.x;               // 512 = 16 boxHi * 4 q * 8 boxLo
  const int boxLo = bid & 7;
  const int r1 = bid >> 3;
  const int q = r1 & 3;
  const int box = ((r1 >> 2) << 3) | boxLo;
  const int t = threadIdx.x;

  if (!ws_keep[box]) return;                // canvas already zeroed in k_prep

  float* mb = out + OFF_MASKS + (size_t)box * 262144;

  const int lane = t & 63, wv = t >> 6;
  const int cq = wv >> 1, half = wv & 1;    // wave = (cq, tile-half)
  const int laneN = lane & 15, kg = lane >> 4;

  // LDS: A (one chunk, 4 cq) 36864 | B (ALL 8 chunks) 73728
  __shared__ __align__(16) unsigned char ldsA[36864];
  __shared__ __align__(16) unsigned char ldsB[73728];
  __shared__ float psum[4][200];            // cq partial logits (196 used)
  __shared__ float softm[7][28];            // this q's soft rows
  __shared__ int   xa_s[MS], xb_s[MS];
  __shared__ float fx_s[MS];
  __shared__ int   ya_s[9], yb_s[9];
  __shared__ float fy_s[9];
  __shared__ float byf[4];
  __shared__ int   bii[4];

  if (t < 4) { byf[t] = ws_boxes[box * 4 + t]; bii[t] = ws_boxint[box * 4 + t]; }
  __syncthreads();
  {
    const float b0 = byf[0] * 0.25f, b1_ = byf[1] * 0.25f;
    const float b2_ = byf[2] * 0.25f, b3_ = byf[3] * 0.25f;
    if (t < MS) {
      float bw = (b2_ - b0) * (1.f / MS);
      float x = b0 + ((float)t + 0.5f) * bw;
      x = fminf(fmaxf(x, 0.f), 127.f);
      int x0 = (int)floorf(x);
      xa_s[t] = x0; xb_s[t] = min(x0 + 1, 127); fx_s[t] = x - (float)x0;
    }
    if (t < 9) {
      int gr = q * 7 + t - 1;               // global mask row for local r=t
      if (gr < 0 || gr > 27) {
        ya_s[t] = -1; yb_s[t] = 0; fy_s[t] = 0.f;
      } else {
        float bh = (b3_ - b1_) * (1.f / MS);
        float yy = b1_ + ((float)gr + 0.5f) * bh;
        yy = fminf(fmaxf(yy, 0.f), 127.f);
        int ya = (int)floorf(yy);
        ya_s[t] = ya; yb_s[t] = min(ya + 1, 127); fy_s[t] = yy - (float)ya;
      }
    }
  }
  __syncthreads();                          // geometry ready for gather

  const unsigned short* mgb = mg + ((size_t)(box >> 6) * 128 * 128) * 256;

  // ---- whole-B gather: 9216 uint2 elements (8 chunks x 9 rows x 128),
  // ---- 18 per thread, register-light phase (acc/ga not yet live).
  #pragma unroll 2
  for (int e = t; e < 9216; e += 512) {
    int ch = e / 1152;
    int inner = e - ch * 1152;
    int r = inner >> 7, rem = inner & 127;
    int cell = rem >> 2, quad = rem & 3;
    unsigned char* dst = ldsB + ch * 9216 + r * 1024 + cell * 32 +
                         ((quad ^ ((cell >> 2) & 3)) << 3);
    int gc = cell - 1;
    int ya = ya_s[r];
    if (gc < 0 || gc > 27 || ya < 0) {
      uint2 z = {0u, 0u};
      *(uint2*)dst = z;
      continue;
    }
    int yb = yb_s[r];
    float fy = fy_s[r];
    int xa = xa_s[gc], xb = xb_s[gc];
    float fx = fx_s[gc];
    float w00 = (1.f - fy) * (1.f - fx), w01 = (1.f - fy) * fx;
    float w10 = fy * (1.f - fx),         w11 = fy * fx;
    const unsigned short* bU = mgb + (size_t)(ch * 4 + quad) * 8;
    uint4 A = *(const uint4*)(bU + (size_t)(ya * 128 + xa) * 256);
    uint4 B = *(const uint4*)(bU + (size_t)(ya * 128 + xb) * 256);
    uint4 C = *(const uint4*)(bU + (size_t)(yb * 128 + xa) * 256);
    uint4 D = *(const uint4*)(bU + (size_t)(yb * 128 + xb) * 256);
    const unsigned* pa = (const unsigned*)&A;
    const unsigned* pb = (const unsigned*)&B;
    const unsigned* pc = (const unsigned*)&C;
    const unsigned* pd = (const unsigned*)&D;
    float f[8];
    #pragma unroll
    for (int k2 = 0; k2 < 4; ++k2) {
      f[2 * k2] = bf2f(pa[k2] & 0xffffu) * w00 + bf2f(pb[k2] & 0xffffu) * w01 +
                  bf2f(pc[k2] & 0xffffu) * w10 + bf2f(pd[k2] & 0xffffu) * w11;
      f[2 * k2 + 1] = bf2f(pa[k2] >> 16) * w00 + bf2f(pb[k2] >> 16) * w01 +
                      bf2f(pc[k2] >> 16) * w10 + bf2f(pd[k2] >> 16) * w11;
    }
    unsigned o0 = __builtin_amdgcn_cvt_pk_fp8_f32(f[0], f[1], 0, false);
    o0 = __builtin_amdgcn_cvt_pk_fp8_f32(f[2], f[3], o0, true);
    unsigned o1 = __builtin_amdgcn_cvt_pk_fp8_f32(f[4], f[5], 0, false);
    o1 = __builtin_amdgcn_cvt_pk_fp8_f32(f[6], f[7], o1, true);
    uint2 pk; pk.x = o0; pk.y = o1;
    *(uint2*)dst = pk;
  }

  // per-(i,dx) swizzled B byte offsets (chunk-relative); tiles: half0 0..6
  int badd[7][3];
  bool act[7];
  #pragma unroll
  for (int i = 0; i < 7; ++i) {
    int tile = half * 7 + i;
    act[i] = tile < 13;
    int p = tile * 16 + laneN;
    if (p > 195) p = 195;
    int py = p / 28, px = p - py * 28;
    #pragma unroll
    for (int dx = 0; dx < 3; ++dx) {
      int cell = px + dx;
      badd[i][dx] = py * 1024 + cell * 32 + (kg ^ ((cell >> 2) & 3)) * 8;
    }
  }
  const int aswz = (kg ^ ((laneN >> 2) & 3)) * 8;

  f32x4 acc[2][7];
  #pragma unroll
  for (int m = 0; m < 2; ++m)
    #pragma unroll
    for (int i = 0; i < 7; ++i) acc[m][i] = (f32x4){0.f, 0.f, 0.f, 0.f};

  const uint4* wbase = (const uint4*)wt;

  uint4 ga0, ga1, ga2, ga3, ga4;  // A staging (2304 uint4 / chunk)
  auto issueA = [&](int c) {
    const uint4* wa = wbase + (size_t)c * 2304;
    ga0 = wa[t]; ga1 = wa[t + 512]; ga2 = wa[t + 1024]; ga3 = wa[t + 1536];
    if (t < 256) ga4 = wa[t + 2048];
  };
  auto writeA = [&]() {
    uint4* da = (uint4*)ldsA;
    da[t] = ga0; da[t + 512] = ga1; da[t + 1024] = ga2; da[t + 1536] = ga3;
    if (t < 256) da[t + 2048] = ga4;
  };

  issueA(0);
  const unsigned char* la = ldsA + (size_t)cq * 9216;  // this wave's A slice
  __syncthreads();                                     // B_all ready

  #pragma unroll 1
  for (int c = 0; c < 8; ++c) {
    writeA();
    __syncthreads();                 // A(c) visible to all waves
    if (c < 7) issueA(c + 1);        // A loads in flight across compute
    const unsigned char* bb = ldsB + c * 9216;
    #pragma unroll
    for (int tap = 0; tap < 9; ++tap) {
      const int dy = tap / 3, dx = tap - dy * 3;
      fp8x8 av0 = *(const fp8x8*)(la + tap * 1024 + laneN * 32 + aswz);
      fp8x8 av1 = *(const fp8x8*)(la + tap * 1024 + 512 + laneN * 32 + aswz);
      #pragma unroll
      for (int i = 0; i < 7; ++i) {
        if (act[i]) {
          fp8x8 bv = *(const fp8x8*)(bb + badd[i][dx] + dy * 1024);
          acc[0][i] = __builtin_amdgcn_mfma_f32_16x16x32_fp8_fp8(av0, bv, acc[0][i], 0, 0, 0);
          acc[1][i] = __builtin_amdgcn_mfma_f32_16x16x32_fp8_fp8(av1, bv, acc[1][i], 0, 0, 0);
        }
      }
    }
    __syncthreads();   // all waves done reading ldsA before next overwrite
  }

  // ---- epilogue: +b1, SiLU, dot w2 over this wave's 32 co, shfl-reduce kg
  {
    float b1v[2][4], w2v[2][4];
    #pragma unroll
    for (int m = 0; m < 2; ++m)
      #pragma unroll
      for (int r = 0; r < 4; ++r) {
        int co = cq * 32 + m * 16 + kg * 4 + r;
        b1v[m][r] = b1[co];
        w2v[m][r] = w2[co];
      }
    #pragma unroll
    for (int i = 0; i < 7; ++i) {
      if (!act[i]) continue;
      float part = 0.f;
      #pragma unroll
      for (int m = 0; m < 2; ++m)
        #pragma unroll
        for (int r = 0; r < 4; ++r) {
          float h = acc[m][i][r] + b1v[m][r];
          part = fmaf(w2v[m][r], h * sigmoidf_(h), part);
        }
      part += __shfl_xor(part, 16);
      part += __shfl_xor(part, 32);
      int p = (half * 7 + i) * 16 + laneN;
      if (kg == 0 && p < 196)
        psum[cq][p] = part;
    }
  }
  __syncthreads();

  // ---- soft rows: sum cq partials (same order as before) + b2, sigmoid
  if (t < 196) {
    float s = sigmoidf_(psum[0][t] + psum[1][t] + psum[2][t] + psum[3][t] + b2[0]);
    softm[t / 28][t % 28] = s;
  }
  __syncthreads();

  // ---- paste ONLY inside-box rows whose iy is in [q*7,(q+1)*7)
  {
    const int x0 = bii[0], y0 = bii[1], x1 = bii[2], y1 = bii[3];
    const int w = x1 - x0 + 1, h = y1 - y0 + 1;

    int Ylo = y0 + (q * 7 * h + 27) / 28;
    int Yhi = (q == 3) ? (y1 + 1) : (y0 + ((q + 1) * 7 * h + 27) / 28);
    if (Yhi > y1 + 1) Yhi = y1 + 1;

    const int c4 = (t & 255) * 2;   // 2 cols per thread (v7 store shape)
    const int rr = t >> 8;          // row interleave 0/1
    int ixr[2];
    bool inx[2];
    #pragma unroll
    for (int u = 0; u < 2; ++u) {
      int X = c4 + u;
      int vx = (X - x0) * MS;
      int ix = (vx >= 0) ? (vx / w) : 0;
      ixr[u] = min(max(ix, 0), MS - 1);
      inx[u] = (X >= x0) && (X <= x1);
    }

    #pragma unroll 1
    for (int Y = Ylo + rr; Y < Yhi; Y += 2) {
      int vy = (Y - y0) * MS;
      int iy = min(vy / h, MS - 1);         // Y in [y0,y1] => vy >= 0
      const float* srow = &softm[iy - q * 7][0];
      f32x2 o;
      o.x = (inx[0] && srow[ixr[0]] > 0.5f) ? 1.f : 0.f;
      o.y = (inx[1] && srow[ixr[1]] > 0.5f) ? 1.f : 0.f;
      __builtin_nontemporal_store(o, (f32x2*)(mb + (size_t)Y * 512 + c4));
    }
  }
}

extern "C" void kernel_launch(void* const* d_in, const int* in_sizes, int n_in,
                              void* d_out, int out_size, void* d_ws, size_t ws_size,
                              hipStream_t stream) {
  const float* p0 = (const float*)d_in[0];
  const float* p1 = (const float*)d_in[1];
  const float* p2 = (const float*)d_in[2];
  const float* p3 = (const float*)d_in[3];
  const float* f0 = (const float*)d_in[4];
  const float* f1 = (const float*)d_in[5];
  const float* f2 = (const float*)d_in[6];
  const float* f3 = (const float*)d_in[7];
  const float* w1 = (const float*)d_in[8];
  const float* b1 = (const float*)d_in[9];
  const float* w2 = (const float*)d_in[10];
  const float* b2 = (const float*)d_in[11];
  float* out = (float*)d_out;

  float* wsf = (float*)d_ws;
  float*          ws_boxes  = wsf;                                // 512 f32
  int*            ws_keep   = (int*)(wsf + 512);                  // 128
  int*            ws_boxint = (int*)(wsf + 640);                  // 512
  unsigned char*  ws_wt     = (unsigned char*)(wsf + 402560);     // 8*4*9*1024 fp8
  unsigned short* ws_merged = (unsigned short*)(wsf + 476288);    // 2*128*128*256 bf16

  k_prep<<<898, 256, 0, stream>>>(p0, p1, p2, p3, f0, f1, f2, f3, w1,
                                  out, ws_boxes, ws_keep, ws_boxint,
                                  ws_wt, ws_merged);
  k_conv<<<512, 512, 0, stream>>>(ws_merged, ws_wt, b1, w2, b2,
                                  ws_boxes, ws_keep, ws_boxint, out);
}

// Round 14
// 246.326 us; speedup vs baseline: 1.0730x; 1.0730x over previous
//
#include <hip/hip_runtime.h>
#include <hip/hip_bf16.h>
#include <cstdint>

#define NTOPK 64
#define A_TOT 340
#define MS 28

// d_out element offsets (f32)
#define OFF_SCORES 0
#define OFF_BOXES  128
#define OFF_LABELS 640
#define OFF_MASKS  768
#define OFF_KEEP   33555200ull

typedef __attribute__((ext_vector_type(4))) float f32x4;
typedef __attribute__((ext_vector_type(2))) float f32x2;
typedef long fp8x8;   // 8 x e4m3 in one 64-bit reg pair

__device__ __forceinline__ float sigmoidf_(float x) { return 1.f / (1.f + expf(-x)); }
__device__ __forceinline__ float bf2f(unsigned u) {
  return __uint_as_float(u << 16);
}
__device__ __forceinline__ unsigned short f2bf(float f) {
  __hip_bfloat16 h = __float2bfloat16(f);  // RNE
  return *(unsigned short*)&h;
}

// ---- Kernel P: fused prep. blocks 0-1: decode+NMS; 2-129: weight transpose;
// ---- 130-385: merged feature build; 386-897: mask canvas zero-fill
// ---- (one 256KB box-quarter each -- balanced streaming, overlaps other work;
// ----  k_conv then only writes inside-box rows).
__global__ __launch_bounds__(256) void k_prep(
    const float* __restrict__ p0, const float* __restrict__ p1,
    const float* __restrict__ p2, const float* __restrict__ p3,
    const float* __restrict__ f0, const float* __restrict__ f1,
    const float* __restrict__ f2, const float* __restrict__ f3,
    const float* __restrict__ w1,
    float* __restrict__ out,
    float* __restrict__ ws_boxes, int* __restrict__ ws_keep,
    int* __restrict__ ws_boxint,
    unsigned char* __restrict__ wt, unsigned short* __restrict__ mg)
{
  __shared__ __align__(16) char smem_raw[128 * 260 * 2];
  const int bid = blockIdx.x;
  const int t = threadIdx.x;

  if (bid >= 386) {
    // ---- mask canvas zero-fill: one quarter (128 rows) of one box
    const int j = bid - 386;                 // 0..511
    float* zb = out + OFF_MASKS + (size_t)(j >> 2) * 262144 +
                (size_t)(j & 3) * 65536;
    f32x4 z = {0.f, 0.f, 0.f, 0.f};
    f32x4* p = (f32x4*)zb;
    for (int e = t; e < 16384; e += 256)
      __builtin_nontemporal_store(z, p + e);
    return;
  }

  if (bid < 2) {
    // ---------------- decode + stable top-64 + shfl NMS ----------------
    const int b = bid;
    float* sc = (float*)smem_raw;                    // [A_TOT]
    float(*bx)[4] = (float(*)[4])(sc + A_TOT);       // [A_TOT][4]
    float* tk_score = (float*)(bx + A_TOT);          // [64]
    float(*tk_box)[4] = (float(*)[4])(tk_score + 64);

    for (int a = t; a < A_TOT; a += 256) {
      const float* pp; int W, HW, la; float stride;
      if (a < 256)      { pp = p0; W = 16; HW = 256; la = a;       stride = 32.f;  }
      else if (a < 320) { pp = p1; W = 8;  HW = 64;  la = a - 256; stride = 64.f;  }
      else if (a < 336) { pp = p2; W = 4;  HW = 16;  la = a - 320; stride = 128.f; }
      else              { pp = p3; W = 2;  HW = 4;   la = a - 336; stride = 256.f; }
      const float* base = pp + (size_t)b * 6 * HW + la;
      float v0 = base[0], v1 = base[HW], v2 = base[2 * HW], v3 = base[3 * HW], v4 = base[4 * HW];
      int gx = la % W, gy = la / W;
      float cx = (v0 + (float)gx) * stride;
      float cy = (v1 + (float)gy) * stride;
      float w_ = expf(v2) * stride;
      float h_ = expf(v3) * stride;
      float score = sigmoidf_(v4);
      sc[a] = (score > 0.5f) ? score : 0.f;
      bx[a][0] = cx - 0.5f * w_;
      bx[a][1] = cy - 0.5f * h_;
      bx[a][2] = cx + 0.5f * w_;
      bx[a][3] = cy + 0.5f * h_;
    }
    __syncthreads();

    // stable top-k by rank counting (ties -> lower index, like lax.top_k)
    for (int a = t; a < A_TOT; a += 256) {
      float my = sc[a];
      int rank = 0;
      for (int j = 0; j < A_TOT; ++j) {
        float o = sc[j];
        rank += (o > my) || (o == my && j < a);
      }
      if (rank < NTOPK) {
        tk_score[rank] = my;
        tk_box[rank][0] = bx[a][0];
        tk_box[rank][1] = bx[a][1];
        tk_box[rank][2] = bx[a][2];
        tk_box[rank][3] = bx[a][3];
      }
    }
    __syncthreads();

    // wave-synchronous sequential NMS on wave 0
    if (t < NTOPK) {
      float x0 = tk_box[t][0], y0 = tk_box[t][1];
      float x1 = tk_box[t][2], y1 = tk_box[t][3];
      float s = tk_score[t];
      float area = fmaxf(x1 - x0, 0.f) * fmaxf(y1 - y0, 0.f);
      int keep = (s > 0.5f) ? 1 : 0;
      for (int i = 0; i < NTOPK - 1; ++i) {
        int   ki = __shfl(keep, i);
        float a0 = __shfl(x0, i);
        float c0 = __shfl(y0, i);
        float a1 = __shfl(x1, i);
        float c1 = __shfl(y1, i);
        float ai = __shfl(area, i);
        if (ki && t > i && keep) {
          float ix0 = fmaxf(a0, x0), iy0 = fmaxf(c0, y0);
          float ix1 = fminf(a1, x1), iy1 = fminf(c1, y1);
          float inter = fmaxf(ix1 - ix0, 0.f) * fmaxf(iy1 - iy0, 0.f);
          float uni = ai + area - inter;
          float iou = inter / fmaxf(uni, 1e-9f);
          if (iou > 0.5f) keep = 0;
        }
      }
      int box = b * NTOPK + t;
      out[OFF_SCORES + box] = keep ? s : 0.f;
      float bv[4] = {x0, y0, x1, y1};
      #pragma unroll
      for (int c = 0; c < 4; ++c) {
        out[OFF_BOXES + box * 4 + c] = bv[c];
        ws_boxes[box * 4 + c] = bv[c];
        float bc = fminf(fmaxf(bv[c], 0.f), 511.f);
        ws_boxint[box * 4 + c] = (int)bc;
      }
      out[OFF_LABELS + box] = 0.f;
      out[OFF_KEEP + box] = keep ? 1.f : 0.f;
      ws_keep[box] = keep;
    }
    return;
  }

  if (bid < 130) {
    // -- w1 f32 [co][ci][3][3] -> wt fp8 [chunk][cq][tap][co32][ci32] with
    // -- octet swizzle baked in: octet slot = (cil>>3) ^ ((col>>2)&3).
    const int co = bid - 2;
    const int ci = t;            // 0..255
    const int c = ci >> 5, cil = ci & 31;
    const int cq = co >> 5, col = co & 31;
    const int slot = ((cil >> 3) ^ ((col >> 2) & 3)) * 8 + (cil & 7);
    const float* src = w1 + ((size_t)co * 256 + ci) * 9;
    #pragma unroll
    for (int tap = 0; tap < 9; ++tap) {
      unsigned u = __builtin_amdgcn_cvt_pk_fp8_f32(src[tap], 0.f, 0, false);
      wt[(((size_t)(c * 4 + cq) * 9 + tap)) * 1024 + col * 32 + slot] =
          (unsigned char)(u & 0xff);
    }
    return;
  }

  // -------- merged[b][y][x][c] bf16 build --------
  {
    const int idx = bid - 130;
    const int b = idx >> 7;
    const int y = idx & 127;
    unsigned short* tile = (unsigned short*)smem_raw;   // [128*260]
    const int x = t & 127, ch = t >> 7;

    {
      const float* src = f0 + ((size_t)b * 64) * 16384 + y * 128 + x;
      for (int cc = 0; cc < 32; ++cc) {
        int cl = ch * 32 + cc;
        tile[x * 260 + cl] = f2bf(src[(size_t)cl * 16384]);
      }
    }
    {
      const float* src = f1 + ((size_t)b * 64) * 4096 + (y >> 1) * 64 + (x >> 1);
      for (int cc = 0; cc < 32; ++cc) {
        int cl = ch * 32 + cc;
        tile[x * 260 + 64 + cl] = f2bf(src[(size_t)cl * 4096]);
      }
    }
    {
      const float* src = f2 + ((size_t)b * 64) * 1024 + (y >> 2) * 32 + (x >> 2);
      for (int cc = 0; cc < 32; ++cc) {
        int cl = ch * 32 + cc;
        tile[x * 260 + 128 + cl] = f2bf(src[(size_t)cl * 1024]);
      }
    }
    {
      const float* src = f3 + ((size_t)b * 64) * 256 + (y >> 3) * 16 + (x >> 3);
      for (int cc = 0; cc < 32; ++cc) {
        int cl = ch * 32 + cc;
        tile[x * 260 + 192 + cl] = f2bf(src[(size_t)cl * 256]);
      }
    }
    __syncthreads();
    unsigned short* dst = mg + (((size_t)b * 128 + y) * 128) * 256;
    for (int it = 0; it < 32; ++it) {
      int qq = t + it * 256;
      int xx = qq >> 6, cg = qq & 63;
      *(ushort4*)(dst + xx * 256 + cg * 4) = *(ushort4*)&tile[xx * 260 + cg * 4];
    }
  }
}

// ==== Kernel F v10 (restored verbatim -- session best, 248.3us total):
// v7 core with the write tail removed -- canvas pre-zeroed in k_prep, so:
// !keep -> bare return; paste writes ONLY rows [y0,y1] in this q's quarter.
// v11 (gather reg-pipeline), v12 (packed gather math), v13 (whole-B LDS
// hoist) all regressed: the gather region tolerates exactly one transient
// 4x-uint4 load set (spill cliff at 128 VGPR) and the schedule needs
// 2 blocks/CU co-residency (occupancy cliff). v10 sits between the cliffs.
__global__ __launch_bounds__(512, 4) void k_conv(
    const unsigned short* __restrict__ mg,  // merged [b][y][x][c] bf16
    const unsigned char* __restrict__ wt,   // [c][cq][tap][co32][ci32^swz]
    const float* __restrict__ b1, const float* __restrict__ w2,
    const float* __restrict__ b2,
    const float* __restrict__ ws_boxes, const int* __restrict__ ws_keep,
    const int* __restrict__ ws_boxint,
    float* __restrict__ out)
{
  const int bid = blockIdx.x;               // 512 = 16 boxHi * 4 q * 8 boxLo
  const int boxLo = bid & 7;
  const int r1 = bid >> 3;
  const int q = r1 & 3;
  const int box = ((r1 >> 2) << 3) | boxLo;
  const int t = threadIdx.x;

  if (!ws_keep[box]) return;                // canvas already zeroed in k_prep

  float* mb = out + OFF_MASKS + (size_t)box * 262144;

  const int lane = t & 63, wv = t >> 6;
  const int cq = wv >> 1, half = wv & 1;    // wave = (cq, tile-half)
  const int laneN = lane & 15, kg = lane >> 4;

  // LDS: A 36864 | B 9216
  __shared__ __align__(16) unsigned char lds[46080];
  __shared__ float psum[4][200];            // cq partial logits (196 used)
  __shared__ float softm[7][28];            // this q's soft rows
  __shared__ int   xa_s[MS], xb_s[MS];
  __shared__ float fx_s[MS];
  __shared__ int   ya_s[9], yb_s[9];
  __shared__ float fy_s[9];
  __shared__ float byf[4];
  __shared__ int   bii[4];

  if (t < 4) { byf[t] = ws_boxes[box * 4 + t]; bii[t] = ws_boxint[box * 4 + t]; }
  __syncthreads();
  {
    const float b0 = byf[0] * 0.25f, b1_ = byf[1] * 0.25f;
    const float b2_ = byf[2] * 0.25f, b3_ = byf[3] * 0.25f;
    if (t < MS) {
      float bw = (b2_ - b0) * (1.f / MS);
      float x = b0 + ((float)t + 0.5f) * bw;
      x = fminf(fmaxf(x, 0.f), 127.f);
      int x0 = (int)floorf(x);
      xa_s[t] = x0; xb_s[t] = min(x0 + 1, 127); fx_s[t] = x - (float)x0;
    }
    if (t < 9) {
      int gr = q * 7 + t - 1;               // global mask row for local r=t
      if (gr < 0 || gr > 27) {
        ya_s[t] = -1; yb_s[t] = 0; fy_s[t] = 0.f;
      } else {
        float bh = (b3_ - b1_) * (1.f / MS);
        float yy = b1_ + ((float)gr + 0.5f) * bh;
        yy = fminf(fmaxf(yy, 0.f), 127.f);
        int ya = (int)floorf(yy);
        ya_s[t] = ya; yb_s[t] = min(ya + 1, 127); fy_s[t] = yy - (float)ya;
      }
    }
  }

  // per-(i,dx) swizzled B byte offsets; tiles: half0 0..6, half1 7..12
  int badd[7][3];
  bool act[7];
  #pragma unroll
  for (int i = 0; i < 7; ++i) {
    int tile = half * 7 + i;
    act[i] = tile < 13;
    int p = tile * 16 + laneN;
    if (p > 195) p = 195;
    int py = p / 28, px = p - py * 28;
    #pragma unroll
    for (int dx = 0; dx < 3; ++dx) {
      int cell = px + dx;
      badd[i][dx] = 36864 + py * 1024 + cell * 32 + (kg ^ ((cell >> 2) & 3)) * 8;
    }
  }
  const int aswz = (kg ^ ((laneN >> 2) & 3)) * 8;

  f32x4 acc[2][7];
  #pragma unroll
  for (int m = 0; m < 2; ++m)
    #pragma unroll
    for (int i = 0; i < 7; ++i) acc[m][i] = (f32x4){0.f, 0.f, 0.f, 0.f};

  const uint4* wbase = (const uint4*)wt;
  const unsigned short* mgb = mg + ((size_t)(box >> 6) * 128 * 128) * 256;

  uint4 ga0, ga1, ga2, ga3, ga4;  // A staging (2304 uint4 / chunk)
  auto issueA = [&](int c) {
    const uint4* wa = wbase + (size_t)c * 2304;
    ga0 = wa[t]; ga1 = wa[t + 512]; ga2 = wa[t + 1024]; ga3 = wa[t + 1536];
    if (t < 256) ga4 = wa[t + 2048];
  };
  auto writeA = [&]() {
    uint4* da = (uint4*)lds;
    da[t] = ga0; da[t + 512] = ga1; da[t + 1024] = ga2; da[t + 1536] = ga3;
    if (t < 256) da[t + 2048] = ga4;
  };

  issueA(0);
  const unsigned char* la = lds + (size_t)cq * 9216;   // this wave's A slice
  __syncthreads();                                     // geometry ready

  #pragma unroll 1
  for (int c = 0; c < 8; ++c) {
    writeA();
    // ---- stage B(c) by bilinear from merged (byte-identical to v7)
    #pragma unroll 1
    for (int e = t; e < 1152; e += 512) {
      int r = e >> 7, rem = e & 127;
      int cell = rem >> 2, quad = rem & 3;
      unsigned char* dst = lds + 36864 + r * 1024 + cell * 32 +
                           ((quad ^ ((cell >> 2) & 3)) << 3);
      int gc = cell - 1;
      int ya = ya_s[r];
      if (gc < 0 || gc > 27 || ya < 0) {
        uint2 z = {0u, 0u};
        *(uint2*)dst = z;
        continue;
      }
      int yb = yb_s[r];
      float fy = fy_s[r];
      int xa = xa_s[gc], xb = xb_s[gc];
      float fx = fx_s[gc];
      float w00 = (1.f - fy) * (1.f - fx), w01 = (1.f - fy) * fx;
      float w10 = fy * (1.f - fx),         w11 = fy * fx;
      const unsigned short* bU = mgb + (size_t)(c * 4 + quad) * 8;
      uint4 A = *(const uint4*)(bU + (size_t)(ya * 128 + xa) * 256);
      uint4 B = *(const uint4*)(bU + (size_t)(ya * 128 + xb) * 256);
      uint4 C = *(const uint4*)(bU + (size_t)(yb * 128 + xa) * 256);
      uint4 D = *(const uint4*)(bU + (size_t)(yb * 128 + xb) * 256);
      const unsigned* pa = (const unsigned*)&A;
      const unsigned* pb = (const unsigned*)&B;
      const unsigned* pc = (const unsigned*)&C;
      const unsigned* pd = (const unsigned*)&D;
      float f[8];
      #pragma unroll
      for (int k2 = 0; k2 < 4; ++k2) {
        f[2 * k2] = bf2f(pa[k2] & 0xffffu) * w00 + bf2f(pb[k2] & 0xffffu) * w01 +
                    bf2f(pc[k2] & 0xffffu) * w10 + bf2f(pd[k2] & 0xffffu) * w11;
        f[2 * k2 + 1] = bf2f(pa[k2] >> 16) * w00 + bf2f(pb[k2] >> 16) * w01 +
                        bf2f(pc[k2] >> 16) * w10 + bf2f(pd[k2] >> 16) * w11;
      }
      unsigned o0 = __builtin_amdgcn_cvt_pk_fp8_f32(f[0], f[1], 0, false);
      o0 = __builtin_amdgcn_cvt_pk_fp8_f32(f[2], f[3], o0, true);
      unsigned o1 = __builtin_amdgcn_cvt_pk_fp8_f32(f[4], f[5], 0, false);
      o1 = __builtin_amdgcn_cvt_pk_fp8_f32(f[6], f[7], o1, true);
      uint2 pk; pk.x = o0; pk.y = o1;
      *(uint2*)dst = pk;
    }
    __syncthreads();
    if (c < 7) issueA(c + 1);       // A loads in flight across compute
    #pragma unroll
    for (int tap = 0; tap < 9; ++tap) {
      const int dy = tap / 3, dx = tap - dy * 3;
      fp8x8 av0 = *(const fp8x8*)(la + tap * 1024 + laneN * 32 + aswz);
      fp8x8 av1 = *(const fp8x8*)(la + tap * 1024 + 512 + laneN * 32 + aswz);
      #pragma unroll
      for (int i = 0; i < 7; ++i) {
        if (act[i]) {
          fp8x8 bv = *(const fp8x8*)(lds + badd[i][dx] + dy * 1024);
          acc[0][i] = __builtin_amdgcn_mfma_f32_16x16x32_fp8_fp8(av0, bv, acc[0][i], 0, 0, 0);
          acc[1][i] = __builtin_amdgcn_mfma_f32_16x16x32_fp8_fp8(av1, bv, acc[1][i], 0, 0, 0);
        }
      }
    }
    __syncthreads();   // all waves done reading before next overwrite
  }

  // ---- epilogue: +b1, SiLU, dot w2 over this wave's 32 co, shfl-reduce kg
  {
    float b1v[2][4], w2v[2][4];
    #pragma unroll
    for (int m = 0; m < 2; ++m)
      #pragma unroll
      for (int r = 0; r < 4; ++r) {
        int co = cq * 32 + m * 16 + kg * 4 + r;
        b1v[m][r] = b1[co];
        w2v[m][r] = w2[co];
      }
    #pragma unroll
    for (int i = 0; i < 7; ++i) {
      if (!act[i]) continue;
      float part = 0.f;
      #pragma unroll
      for (int m = 0; m < 2; ++m)
        #pragma unroll
        for (int r = 0; r < 4; ++r) {
          float h = acc[m][i][r] + b1v[m][r];
          part = fmaf(w2v[m][r], h * sigmoidf_(h), part);
        }
      part += __shfl_xor(part, 16);
      part += __shfl_xor(part, 32);
      int p = (half * 7 + i) * 16 + laneN;
      if (kg == 0 && p < 196)
        psum[cq][p] = part;
    }
  }
  __syncthreads();

  // ---- soft rows: sum cq partials (same order as before) + b2, sigmoid
  if (t < 196) {
    float s = sigmoidf_(psum[0][t] + psum[1][t] + psum[2][t] + psum[3][t] + b2[0]);
    softm[t / 28][t % 28] = s;
  }
  __syncthreads();

  // ---- paste ONLY inside-box rows whose iy is in [q*7,(q+1)*7)
  {
    const int x0 = bii[0], y0 = bii[1], x1 = bii[2], y1 = bii[3];
    const int w = x1 - x0 + 1, h = y1 - y0 + 1;

    int Ylo = y0 + (q * 7 * h + 27) / 28;
    int Yhi = (q == 3) ? (y1 + 1) : (y0 + ((q + 1) * 7 * h + 27) / 28);
    if (Yhi > y1 + 1) Yhi = y1 + 1;

    const int c4 = (t & 255) * 2;   // 2 cols per thread (v7 store shape)
    const int rr = t >> 8;          // row interleave 0/1
    int ixr[2];
    bool inx[2];
    #pragma unroll
    for (int u = 0; u < 2; ++u) {
      int X = c4 + u;
      int vx = (X - x0) * MS;
      int ix = (vx >= 0) ? (vx / w) : 0;
      ixr[u] = min(max(ix, 0), MS - 1);
      inx[u] = (X >= x0) && (X <= x1);
    }

    #pragma unroll 1
    for (int Y = Ylo + rr; Y < Yhi; Y += 2) {
      int vy = (Y - y0) * MS;
      int iy = min(vy / h, MS - 1);         // Y in [y0,y1] => vy >= 0
      const float* srow = &softm[iy - q * 7][0];
      f32x2 o;
      o.x = (inx[0] && srow[ixr[0]] > 0.5f) ? 1.f : 0.f;
      o.y = (inx[1] && srow[ixr[1]] > 0.5f) ? 1.f : 0.f;
      __builtin_nontemporal_store(o, (f32x2*)(mb + (size_t)Y * 512 + c4));
    }
  }
}

extern "C" void kernel_launch(void* const* d_in, const int* in_sizes, int n_in,
                              void* d_out, int out_size, void* d_ws, size_t ws_size,
                              hipStream_t stream) {
  const float* p0 = (const float*)d_in[0];
  const float* p1 = (const float*)d_in[1];
  const float* p2 = (const float*)d_in[2];
  const float* p3 = (const float*)d_in[3];
  const float* f0 = (const float*)d_in[4];
  const float* f1 = (const float*)d_in[5];
  const float* f2 = (const float*)d_in[6];
  const float* f3 = (const float*)d_in[7];
  const float* w1 = (const float*)d_in[8];
  const float* b1 = (const float*)d_in[9];
  const float* w2 = (const float*)d_in[10];
  const float* b2 = (const float*)d_in[11];
  float* out = (float*)d_out;

  float* wsf = (float*)d_ws;
  float*          ws_boxes  = wsf;                                // 512 f32
  int*            ws_keep   = (int*)(wsf + 512);                  // 128
  int*            ws_boxint = (int*)(wsf + 640);                  // 512
  unsigned char*  ws_wt     = (unsigned char*)(wsf + 402560);     // 8*4*9*1024 fp8
  unsigned short* ws_merged = (unsigned short*)(wsf + 476288);    // 2*128*128*256 bf16

  k_prep<<<898, 256, 0, stream>>>(p0, p1, p2, p3, f0, f1, f2, f3, w1,
                                  out, ws_boxes, ws_keep, ws_boxint,
                                  ws_wt, ws_merged);
  k_conv<<<512, 512, 0, stream>>>(ws_merged, ws_wt, b1, w2, b2,
                                  ws_boxes, ws_keep, ws_boxint, out);
}